// Round 1
// baseline (3385.010 us; speedup 1.0000x reference)
//
#include <hip/hip_runtime.h>
#include <hip/hip_bf16.h>
#include <hip/hip_cooperative_groups.h>

namespace cg = cooperative_groups;

#define VOCAB 32000
#define EMBED 256
#define HIDDEN 512
#define BB 64
#define SS 64
#define M_ROWS (BB * SS)       /* 4096 */
#define KIN (EMBED + HIDDEN)   /* 768  */
#define G4 (4 * HIDDEN)        /* 2048 */
#define KOUT (2 * HIDDEN)      /* 1024 */

typedef __attribute__((ext_vector_type(8))) short short8v;
typedef __attribute__((ext_vector_type(4))) float float4v;

__device__ __forceinline__ ushort f2bf(float f) {
    union { float f; unsigned u; } v; v.f = f;
    unsigned r = (v.u + 0x7FFFu + ((v.u >> 16) & 1u)) >> 16;
    return (ushort)r;
}

__global__ void k_f32_to_bf16(const float* __restrict__ in, ushort* __restrict__ out, int n) {
    int i = blockIdx.x * blockDim.x + threadIdx.x;
    int stride = gridDim.x * blockDim.x;
    for (; i < n; i += stride) out[i] = f2bf(in[i]);
}

__global__ void k_build_lstm_in(const int* __restrict__ tseq, const float* __restrict__ emb,
                                const float* __restrict__ ctx, ushort* __restrict__ lstm_in) {
    int rid = blockIdx.x;             // 0..4095  (= b*64 + s)
    int tok = tseq[rid];
    int b = rid >> 6;
    for (int f = threadIdx.x; f < KIN; f += blockDim.x) {
        float v = (f < EMBED) ? emb[tok * EMBED + f] : ctx[b * HIDDEN + (f - EMBED)];
        lstm_in[(size_t)rid * KIN + f] = f2bf(v);
    }
}

__global__ void k_fill_outin_ctx(const float* __restrict__ ctx, ushort* __restrict__ out_in) {
    int rid = blockIdx.x;
    int b = rid >> 6;
    for (int j = threadIdx.x; j < HIDDEN; j += blockDim.x)
        out_in[(size_t)rid * KOUT + HIDDEN + j] = f2bf(ctx[b * HIDDEN + j]);
}

__global__ void k_prep_small(const float* __restrict__ b_ih, const float* __restrict__ b_hh,
                             float* __restrict__ bias_pre,
                             const float* __restrict__ h0, const float* __restrict__ c0,
                             float* __restrict__ hT0, float* __restrict__ cT) {
    int i = blockIdx.x * blockDim.x + threadIdx.x;
    if (i < G4) bias_pre[i] = b_ih[i] + b_hh[i];
    if (i < BB * HIDDEN) {
        int b = i >> 9, j = i & 511;
        hT0[j * BB + b] = h0[i];
        cT[j * BB + b] = c0[i];
    }
}

// C[M][N] = A[M][K](bf16) @ W[N][K]^T(bf16) + bias[N], fp32 out.
// 128x128 tile, 4 waves (2x2), each wave 4x4 16x16x32 MFMA fragments.
__global__ __launch_bounds__(256) void k_gemm_bf16(
    const ushort* __restrict__ A, const ushort* __restrict__ W,
    const float* __restrict__ bias, float* __restrict__ C,
    int M, int N, int K) {
    __shared__ ushort As[128][40];   // +8 pad: 80B rows -> ~2-way (free) on ds_read_b128
    __shared__ ushort Ws[128][40];
    int t = threadIdx.x;
    int brow = blockIdx.y * 128, bcol = blockIdx.x * 128;
    int wave = t >> 6, lane = t & 63;
    int wr = wave >> 1, wc = wave & 1;
    int lr = lane & 15, kg = lane >> 4;

    float4v acc[4][4];
#pragma unroll
    for (int m = 0; m < 4; m++)
#pragma unroll
        for (int n = 0; n < 4; n++) acc[m][n] = (float4v){0.f, 0.f, 0.f, 0.f};

    int r0 = t >> 2;
    int kc = (t & 3) * 8;
    const ushort* Ag  = A + (size_t)(brow + r0) * K + kc;
    const ushort* Ag2 = Ag + (size_t)64 * K;
    const ushort* Wg  = W + (size_t)(bcol + r0) * K + kc;
    const ushort* Wg2 = Wg + (size_t)64 * K;

    for (int bk = 0; bk < K; bk += 32) {
        *(uint4*)&As[r0][kc]      = *(const uint4*)(Ag + bk);
        *(uint4*)&As[r0 + 64][kc] = *(const uint4*)(Ag2 + bk);
        *(uint4*)&Ws[r0][kc]      = *(const uint4*)(Wg + bk);
        *(uint4*)&Ws[r0 + 64][kc] = *(const uint4*)(Wg2 + bk);
        __syncthreads();
        short8v a[4], w[4];
#pragma unroll
        for (int m = 0; m < 4; m++) a[m] = *(const short8v*)&As[wr * 64 + m * 16 + lr][kg * 8];
#pragma unroll
        for (int n = 0; n < 4; n++) w[n] = *(const short8v*)&Ws[wc * 64 + n * 16 + lr][kg * 8];
#pragma unroll
        for (int m = 0; m < 4; m++)
#pragma unroll
            for (int n = 0; n < 4; n++)
                acc[m][n] = __builtin_amdgcn_mfma_f32_16x16x32_bf16(a[m], w[n], acc[m][n], 0, 0, 0);
        __syncthreads();
    }

#pragma unroll
    for (int n = 0; n < 4; n++) {
        int col = bcol + wc * 64 + n * 16 + lr;
        float bv = bias[col];
#pragma unroll
        for (int m = 0; m < 4; m++) {
            int row = brow + wr * 64 + m * 16 + kg * 4;
            float4v v = acc[m][n];
#pragma unroll
            for (int j = 0; j < 4; j++)
                C[(size_t)(row + j) * N + col] = v[j] + bv;
        }
    }
}

// Cooperative LSTM: 256 blocks x 256 threads. Block p owns hidden cols {2p, 2p+1}
// (8 gate rows). h kept transposed [512][64] fp32, double-buffered. 1 grid.sync/step.
__global__ __launch_bounds__(256) void k_lstm(
    const float* __restrict__ pre, const float* __restrict__ w_hh,
    float* __restrict__ hTa, float* __restrict__ hTb, float* __restrict__ cT,
    ushort* __restrict__ out_in) {
    __shared__ float gates_lds[8][64];
    cg::grid_group grid = cg::this_grid();
    int p = blockIdx.x;
    int t = threadIdx.x;
    int j0 = p * 2;
    int b = t & 63;
    int q = t >> 6;  // gate index 0..3 (wave-uniform)
    int rbase = __builtin_amdgcn_readfirstlane((q * HIDDEN + j0) * HIDDEN);
    const float* w0 = w_hh + rbase;           // row (q,j0)
    const float* w1 = w_hh + rbase + HIDDEN;  // row (q,j0+1)

    for (int s = 0; s < SS; s++) {
        const float* hT = (s & 1) ? hTb : hTa;
        float* hTn = (s & 1) ? hTa : hTb;
        float acc0 = 0.f, acc1 = 0.f;
#pragma unroll 8
        for (int k = 0; k < HIDDEN; k++) {
            float hv = hT[k * BB + b];
            acc0 += hv * w0[k];
            acc1 += hv * w1[k];
        }
        gates_lds[q][b] = acc0;      // (gate q, jj=0)
        gates_lds[q + 4][b] = acc1;  // (gate q, jj=1)
        __syncthreads();
        if (t < 128) {
            int jj = t >> 6;
            int j = j0 + jj;
            size_t pbase = (size_t)(b * SS + s) * G4 + j;
            float xi = gates_lds[4 * jj + 0][b] + pre[pbase];
            float xf = gates_lds[4 * jj + 1][b] + pre[pbase + HIDDEN];
            float xg = gates_lds[4 * jj + 2][b] + pre[pbase + 2 * HIDDEN];
            float xo = gates_lds[4 * jj + 3][b] + pre[pbase + 3 * HIDDEN];
            float ig = 1.f / (1.f + expf(-xi));
            float fg = 1.f / (1.f + expf(-xf));
            float gg = tanhf(xg);
            float og = 1.f / (1.f + expf(-xo));
            float cn = fg * cT[j * BB + b] + ig * gg;
            float hn = og * tanhf(cn);
            cT[j * BB + b] = cn;
            hTn[j * BB + b] = hn;
            out_in[(size_t)(b * SS + s) * KOUT + j] = f2bf(hn);
        }
        grid.sync();
    }
}

extern "C" void kernel_launch(void* const* d_in, const int* in_sizes, int n_in,
                              void* d_out, int out_size, void* d_ws, size_t ws_size,
                              hipStream_t stream) {
    const int*   tseq = (const int*)d_in[0];
    const float* ctx  = (const float*)d_in[1];
    const float* h0   = (const float*)d_in[2];
    const float* c0   = (const float*)d_in[3];
    const float* emb  = (const float*)d_in[4];
    const float* w_ih = (const float*)d_in[5];
    const float* w_hh = (const float*)d_in[6];
    const float* b_ih = (const float*)d_in[7];
    const float* b_hh = (const float*)d_in[8];
    const float* w_fc = (const float*)d_in[9];
    const float* b_fc = (const float*)d_in[10];
    float* out = (float*)d_out;

    char* wsb = (char*)d_ws;
    size_t off = 0;
    auto alloc = [&](size_t bytes) -> void* {
        void* ptr = wsb + off;
        off = (off + bytes + 255) & ~(size_t)255;
        return ptr;
    };
    ushort* lstm_in  = (ushort*)alloc((size_t)M_ROWS * KIN * 2);
    ushort* w_ih_bf  = (ushort*)alloc((size_t)G4 * KIN * 2);
    ushort* w_fc_bf  = (ushort*)alloc((size_t)VOCAB * KOUT * 2);
    ushort* out_in   = (ushort*)alloc((size_t)M_ROWS * KOUT * 2);
    float*  pre      = (float*)alloc((size_t)M_ROWS * G4 * 4);
    float*  hT0      = (float*)alloc((size_t)HIDDEN * BB * 4);
    float*  hT1      = (float*)alloc((size_t)HIDDEN * BB * 4);
    float*  cT       = (float*)alloc((size_t)HIDDEN * BB * 4);
    float*  bias_pre = (float*)alloc((size_t)G4 * 4);

    k_f32_to_bf16<<<1024, 256, 0, stream>>>(w_ih, w_ih_bf, G4 * KIN);
    k_f32_to_bf16<<<2048, 256, 0, stream>>>(w_fc, w_fc_bf, VOCAB * KOUT);
    k_build_lstm_in<<<M_ROWS, 256, 0, stream>>>(tseq, emb, ctx, lstm_in);
    k_fill_outin_ctx<<<M_ROWS, 256, 0, stream>>>(ctx, out_in);
    k_prep_small<<<128, 256, 0, stream>>>(b_ih, b_hh, bias_pre, h0, c0, hT0, cT);

    dim3 g1(G4 / 128, M_ROWS / 128);
    k_gemm_bf16<<<g1, 256, 0, stream>>>(lstm_in, w_ih_bf, bias_pre, pre, M_ROWS, G4, KIN);

    void* args[] = {(void*)&pre, (void*)&w_hh, (void*)&hT0, (void*)&hT1, (void*)&cT, (void*)&out_in};
    hipLaunchCooperativeKernel((void*)k_lstm, dim3(256), dim3(256), args, 0, stream);

    dim3 g2(VOCAB / 128, M_ROWS / 128);
    k_gemm_bf16<<<g2, 256, 0, stream>>>(out_in, w_fc_bf, b_fc, out, M_ROWS, VOCAB, KOUT);
}

// Round 2
// 1516.992 us; speedup vs baseline: 2.2314x; 2.2314x over previous
//
#include <hip/hip_runtime.h>
#include <hip/hip_bf16.h>
#include <hip/hip_cooperative_groups.h>

namespace cg = cooperative_groups;

#define VOCAB 32000
#define EMBED 256
#define HIDDEN 512
#define BB 64
#define SS 64
#define M_ROWS (BB * SS)       /* 4096 */
#define KIN (EMBED + HIDDEN)   /* 768  */
#define G4 (4 * HIDDEN)        /* 2048 */
#define KOUT (2 * HIDDEN)      /* 1024 */
#define LJ 8                   /* hidden cols per LSTM block */

typedef __attribute__((ext_vector_type(8))) short short8v;
typedef __attribute__((ext_vector_type(4))) float float4v;

__device__ __forceinline__ ushort f2bf(float f) {
    union { float f; unsigned u; } v; v.f = f;
    unsigned r = (v.u + 0x7FFFu + ((v.u >> 16) & 1u)) >> 16;
    return (ushort)r;
}

__global__ void k_f32_to_bf16(const float* __restrict__ in, ushort* __restrict__ out, int n) {
    int i = blockIdx.x * blockDim.x + threadIdx.x;
    int stride = gridDim.x * blockDim.x;
    for (; i < n; i += stride) out[i] = f2bf(in[i]);
}

__global__ void k_build_lstm_in(const int* __restrict__ tseq, const float* __restrict__ emb,
                                const float* __restrict__ ctx, ushort* __restrict__ lstm_in) {
    int rid = blockIdx.x;             // 0..4095  (= b*64 + s)
    int tok = tseq[rid];
    int b = rid >> 6;
    for (int f = threadIdx.x; f < KIN; f += blockDim.x) {
        float v = (f < EMBED) ? emb[tok * EMBED + f] : ctx[b * HIDDEN + (f - EMBED)];
        lstm_in[(size_t)rid * KIN + f] = f2bf(v);
    }
}

__global__ void k_fill_outin_ctx(const float* __restrict__ ctx, ushort* __restrict__ out_in) {
    int rid = blockIdx.x;
    int b = rid >> 6;
    for (int j = threadIdx.x; j < HIDDEN; j += blockDim.x)
        out_in[(size_t)rid * KOUT + HIDDEN + j] = f2bf(ctx[b * HIDDEN + j]);
}

__global__ void k_prep_small(const float* __restrict__ b_ih, const float* __restrict__ b_hh,
                             float* __restrict__ bias_pre,
                             const float* __restrict__ h0, ushort* __restrict__ hbufA) {
    int i = blockIdx.x * blockDim.x + threadIdx.x;
    if (i < G4) bias_pre[i] = b_ih[i] + b_hh[i];
    if (i < BB * HIDDEN) hbufA[i] = f2bf(h0[i]);
}

// C[M][N] = A[M][K](bf16) @ W[N][K]^T(bf16) + bias[N], fp32 out.
// 128x128 tile, 4 waves (2x2), each wave 4x4 16x16x32 MFMA fragments.
__global__ __launch_bounds__(256) void k_gemm_bf16(
    const ushort* __restrict__ A, const ushort* __restrict__ W,
    const float* __restrict__ bias, float* __restrict__ C,
    int M, int N, int K) {
    __shared__ ushort As[128][40];
    __shared__ ushort Ws[128][40];
    int t = threadIdx.x;
    int brow = blockIdx.y * 128, bcol = blockIdx.x * 128;
    int wave = t >> 6, lane = t & 63;
    int wr = wave >> 1, wc = wave & 1;
    int lr = lane & 15, kg = lane >> 4;

    float4v acc[4][4];
#pragma unroll
    for (int m = 0; m < 4; m++)
#pragma unroll
        for (int n = 0; n < 4; n++) acc[m][n] = (float4v){0.f, 0.f, 0.f, 0.f};

    int r0 = t >> 2;
    int kc = (t & 3) * 8;
    const ushort* Ag  = A + (size_t)(brow + r0) * K + kc;
    const ushort* Ag2 = Ag + (size_t)64 * K;
    const ushort* Wg  = W + (size_t)(bcol + r0) * K + kc;
    const ushort* Wg2 = Wg + (size_t)64 * K;

    for (int bk = 0; bk < K; bk += 32) {
        *(uint4*)&As[r0][kc]      = *(const uint4*)(Ag + bk);
        *(uint4*)&As[r0 + 64][kc] = *(const uint4*)(Ag2 + bk);
        *(uint4*)&Ws[r0][kc]      = *(const uint4*)(Wg + bk);
        *(uint4*)&Ws[r0 + 64][kc] = *(const uint4*)(Wg2 + bk);
        __syncthreads();
        short8v a[4], w[4];
#pragma unroll
        for (int m = 0; m < 4; m++) a[m] = *(const short8v*)&As[wr * 64 + m * 16 + lr][kg * 8];
#pragma unroll
        for (int n = 0; n < 4; n++) w[n] = *(const short8v*)&Ws[wc * 64 + n * 16 + lr][kg * 8];
#pragma unroll
        for (int m = 0; m < 4; m++)
#pragma unroll
            for (int n = 0; n < 4; n++)
                acc[m][n] = __builtin_amdgcn_mfma_f32_16x16x32_bf16(a[m], w[n], acc[m][n], 0, 0, 0);
        __syncthreads();
    }

#pragma unroll
    for (int n = 0; n < 4; n++) {
        int col = bcol + wc * 64 + n * 16 + lr;
        float bv = bias[col];
#pragma unroll
        for (int m = 0; m < 4; m++) {
            int row = brow + wr * 64 + m * 16 + kg * 4;
            float4v v = acc[m][n];
#pragma unroll
            for (int j = 0; j < 4; j++)
                C[(size_t)(row + j) * N + col] = v[j] + bv;
        }
    }
}

// Persistent MFMA LSTM: 64 blocks x 128 threads (2 waves), cooperative.
// Block p owns hidden cols [8p, 8p+8). Wave wv owns 16 gate-cols:
//   lane lr (0..15): q = lr>>2 (gate), u = lr&3, jj = wv*4+u, j = 8p+jj.
// w_hh rows live in registers as bf16 B-fragments (loaded once).
// h broadcast via global bf16 buffer (L3); c stays in thread registers.
__global__ __launch_bounds__(128) void k_lstm(
    const float* __restrict__ pre, const float* __restrict__ w_hh,
    const float* __restrict__ c0,
    ushort* __restrict__ hbufA, ushort* __restrict__ hbufB,
    ushort* __restrict__ out_in) {
    __shared__ float G2[64 * 36];   // [b][jj*4+q], row stride 36 floats
    cg::grid_group grid = cg::this_grid();
    int p = blockIdx.x;
    int t = threadIdx.x;
    int wv = t >> 6, lane = t & 63;
    int lr = lane & 15, kg = lane >> 4;
    int q = lr >> 2, u = lr & 3;
    int jj_w = wv * 4 + u;
    int jg_w = p * LJ + jj_w;
    int wrow = q * HIDDEN + jg_w;

    // one-time: load this lane's w_hh B-fragments (fp32 -> bf16)
    short8v wfrag[16];
#pragma unroll
    for (int ks = 0; ks < 16; ks++) {
        const float* src = w_hh + (size_t)wrow * HIDDEN + ks * 32 + kg * 8;
        float4 v0 = *(const float4*)(src);
        float4 v1 = *(const float4*)(src + 4);
        short8v w8;
        w8[0] = (short)f2bf(v0.x); w8[1] = (short)f2bf(v0.y);
        w8[2] = (short)f2bf(v0.z); w8[3] = (short)f2bf(v0.w);
        w8[4] = (short)f2bf(v1.x); w8[5] = (short)f2bf(v1.y);
        w8[6] = (short)f2bf(v1.z); w8[7] = (short)f2bf(v1.w);
        wfrag[ks] = w8;
    }

    // pointwise state: thread t handles (b = i*16 + (t>>3), jj = t&7), i=0..3
    int jj = t & 7;
    int jg = p * LJ + jj;
    float c_reg[4];
#pragma unroll
    for (int i = 0; i < 4; i++) {
        int b = i * 16 + (t >> 3);
        c_reg[i] = c0[b * HIDDEN + jg];
    }

    for (int s = 0; s < SS; s++) {
        const ushort* hb = (s & 1) ? hbufB : hbufA;
        ushort* hn = (s & 1) ? hbufA : hbufB;

        float4v acc[4];
#pragma unroll
        for (int m = 0; m < 4; m++) acc[m] = (float4v){0.f, 0.f, 0.f, 0.f};
#pragma unroll
        for (int ks = 0; ks < 16; ks++) {
#pragma unroll
            for (int m = 0; m < 4; m++) {
                short8v a = *(const short8v*)(hb + (size_t)(m * 16 + lr) * HIDDEN + ks * 32 + kg * 8);
                acc[m] = __builtin_amdgcn_mfma_f32_16x16x32_bf16(a, wfrag[ks], acc[m], 0, 0, 0);
            }
        }
#pragma unroll
        for (int m = 0; m < 4; m++)
#pragma unroll
            for (int r = 0; r < 4; r++)
                G2[(m * 16 + kg * 4 + r) * 36 + jj_w * 4 + q] = acc[m][r];
        __syncthreads();

#pragma unroll
        for (int i = 0; i < 4; i++) {
            int b = i * 16 + (t >> 3);
            float4 gv = *(const float4*)&G2[b * 36 + jj * 4];
            size_t pb = ((size_t)(b * SS + s)) * G4 + jg;
            float xi = gv.x + pre[pb];
            float xf = gv.y + pre[pb + HIDDEN];
            float xg = gv.z + pre[pb + 2 * HIDDEN];
            float xo = gv.w + pre[pb + 3 * HIDDEN];
            float ig = 1.f / (1.f + __expf(-xi));
            float fg = 1.f / (1.f + __expf(-xf));
            float gg = tanhf(xg);
            float og = 1.f / (1.f + __expf(-xo));
            float cn = fg * c_reg[i] + ig * gg;
            float hv = og * tanhf(cn);
            c_reg[i] = cn;
            ushort hb16 = f2bf(hv);
            hn[b * HIDDEN + jg] = hb16;
            out_in[((size_t)(b * SS + s)) * KOUT + jg] = hb16;
        }
        grid.sync();
    }
}

extern "C" void kernel_launch(void* const* d_in, const int* in_sizes, int n_in,
                              void* d_out, int out_size, void* d_ws, size_t ws_size,
                              hipStream_t stream) {
    const int*   tseq = (const int*)d_in[0];
    const float* ctx  = (const float*)d_in[1];
    const float* h0   = (const float*)d_in[2];
    const float* c0   = (const float*)d_in[3];
    const float* emb  = (const float*)d_in[4];
    const float* w_ih = (const float*)d_in[5];
    const float* w_hh = (const float*)d_in[6];
    const float* b_ih = (const float*)d_in[7];
    const float* b_hh = (const float*)d_in[8];
    const float* w_fc = (const float*)d_in[9];
    const float* b_fc = (const float*)d_in[10];
    float* out = (float*)d_out;

    char* wsb = (char*)d_ws;
    size_t off = 0;
    auto alloc = [&](size_t bytes) -> void* {
        void* ptr = wsb + off;
        off = (off + bytes + 255) & ~(size_t)255;
        return ptr;
    };
    ushort* lstm_in  = (ushort*)alloc((size_t)M_ROWS * KIN * 2);
    ushort* w_ih_bf  = (ushort*)alloc((size_t)G4 * KIN * 2);
    ushort* w_fc_bf  = (ushort*)alloc((size_t)VOCAB * KOUT * 2);
    ushort* out_in   = (ushort*)alloc((size_t)M_ROWS * KOUT * 2);
    float*  pre      = (float*)alloc((size_t)M_ROWS * G4 * 4);
    ushort* hbufA    = (ushort*)alloc((size_t)BB * HIDDEN * 2);
    ushort* hbufB    = (ushort*)alloc((size_t)BB * HIDDEN * 2);
    float*  bias_pre = (float*)alloc((size_t)G4 * 4);

    k_f32_to_bf16<<<1024, 256, 0, stream>>>(w_ih, w_ih_bf, G4 * KIN);
    k_f32_to_bf16<<<2048, 256, 0, stream>>>(w_fc, w_fc_bf, VOCAB * KOUT);
    k_build_lstm_in<<<M_ROWS, 256, 0, stream>>>(tseq, emb, ctx, lstm_in);
    k_fill_outin_ctx<<<M_ROWS, 256, 0, stream>>>(ctx, out_in);
    k_prep_small<<<128, 256, 0, stream>>>(b_ih, b_hh, bias_pre, h0, hbufA);

    dim3 g1(G4 / 128, M_ROWS / 128);
    k_gemm_bf16<<<g1, 256, 0, stream>>>(lstm_in, w_ih_bf, bias_pre, pre, M_ROWS, G4, KIN);

    void* args[] = {(void*)&pre, (void*)&w_hh, (void*)&c0,
                    (void*)&hbufA, (void*)&hbufB, (void*)&out_in};
    hipLaunchCooperativeKernel((void*)k_lstm, dim3(64), dim3(128), args, 0, stream);

    dim3 g2(VOCAB / 128, M_ROWS / 128);
    k_gemm_bf16<<<g2, 256, 0, stream>>>(out_in, w_fc_bf, b_fc, out, M_ROWS, VOCAB, KOUT);
}

// Round 3
// 1447.005 us; speedup vs baseline: 2.3393x; 1.0484x over previous
//
#include <hip/hip_runtime.h>
#include <hip/hip_bf16.h>
#include <hip/hip_cooperative_groups.h>

namespace cg = cooperative_groups;

#define VOCAB 32000
#define EMBED 256
#define HIDDEN 512
#define BB 64
#define SS 64
#define M_ROWS (BB * SS)       /* 4096 */
#define KIN (EMBED + HIDDEN)   /* 768  */
#define G4 (4 * HIDDEN)        /* 2048 */
#define KOUT (2 * HIDDEN)      /* 1024 */
#define LJ 8                   /* hidden cols per LSTM block */

typedef __attribute__((ext_vector_type(8))) short short8v;
typedef __attribute__((ext_vector_type(4))) float float4v;

__device__ __forceinline__ ushort f2bf(float f) {
    union { float f; unsigned u; } v; v.f = f;
    unsigned r = (v.u + 0x7FFFu + ((v.u >> 16) & 1u)) >> 16;
    return (ushort)r;
}

__device__ __forceinline__ float fast_tanh(float x) {
    float xc = fminf(fmaxf(x, -15.f), 15.f);
    float e = __expf(2.f * xc);
    return (e - 1.f) / (e + 1.f);
}

__device__ __forceinline__ void glds16(const ushort* g, ushort* l) {
    __builtin_amdgcn_global_load_lds(
        (const __attribute__((address_space(1))) unsigned int*)(const void*)g,
        (__attribute__((address_space(3))) unsigned int*)(void*)l, 16, 0, 0);
}

__global__ void k_f32_to_bf16(const float* __restrict__ in, ushort* __restrict__ out, int n) {
    int i = blockIdx.x * blockDim.x + threadIdx.x;
    int stride = gridDim.x * blockDim.x;
    for (; i < n; i += stride) out[i] = f2bf(in[i]);
}

__global__ void k_build_lstm_in(const int* __restrict__ tseq, const float* __restrict__ emb,
                                const float* __restrict__ ctx, ushort* __restrict__ lstm_in) {
    int rid = blockIdx.x;             // 0..4095  (= b*64 + s)
    int tok = tseq[rid];
    int b = rid >> 6;
    for (int f = threadIdx.x; f < KIN; f += blockDim.x) {
        float v = (f < EMBED) ? emb[tok * EMBED + f] : ctx[b * HIDDEN + (f - EMBED)];
        lstm_in[(size_t)rid * KIN + f] = f2bf(v);
    }
}

__global__ void k_fill_outin_ctx(const float* __restrict__ ctx, ushort* __restrict__ out_in) {
    int rid = blockIdx.x;
    int b = rid >> 6;
    for (int j = threadIdx.x; j < HIDDEN; j += blockDim.x)
        out_in[(size_t)rid * KOUT + HIDDEN + j] = f2bf(ctx[b * HIDDEN + j]);
}

__global__ void k_prep_small(const float* __restrict__ b_ih, const float* __restrict__ b_hh,
                             float* __restrict__ bias_pre,
                             const float* __restrict__ h0, ushort* __restrict__ hbufA) {
    int i = blockIdx.x * blockDim.x + threadIdx.x;
    if (i < G4) bias_pre[i] = b_ih[i] + b_hh[i];
    if (i < BB * HIDDEN) hbufA[i] = f2bf(h0[i]);
}

// C[M][N] = A[M][K](bf16) @ W[N][K]^T(bf16) + bias[N], fp32 out.
// 128x128 tile, 4 waves (2x2), 4x4 16x16x32 MFMA frags/wave.
// m97 recipe: linear LDS + global_load_lds width-16 staging.
__global__ __launch_bounds__(256) void k_gemm_bf16(
    const ushort* __restrict__ A, const ushort* __restrict__ W,
    const float* __restrict__ bias, float* __restrict__ C,
    int M, int N, int K) {
    __shared__ ushort As[128 * 32];
    __shared__ ushort Ws[128 * 32];
    int t = threadIdx.x;
    int brow = blockIdx.y * 128, bcol = blockIdx.x * 128;
    int wave = t >> 6, lane = t & 63;
    int wr = wave >> 1, wc = wave & 1;
    int lr = lane & 15, kg = lane >> 4;

    float4v acc[4][4];
#pragma unroll
    for (int m = 0; m < 4; m++)
#pragma unroll
        for (int n = 0; n < 4; n++) acc[m][n] = (float4v){0.f, 0.f, 0.f, 0.f};

    // staging: wave stages rows [wave*16, +16) and [64+wave*16, +16); lane l -> row +l/4, col (l&3)*8
    int srow = wave * 16 + (lane >> 2);
    int scol = (lane & 3) * 8;
    const ushort* AgA = A + (size_t)(brow + srow) * K + scol;
    const ushort* AgB = A + (size_t)(brow + 64 + srow) * K + scol;
    const ushort* WgA = W + (size_t)(bcol + srow) * K + scol;
    const ushort* WgB = W + (size_t)(bcol + 64 + srow) * K + scol;
    ushort* ldsA0 = &As[(wave * 16) * 32];
    ushort* ldsA1 = &As[(64 + wave * 16) * 32];
    ushort* ldsW0 = &Ws[(wave * 16) * 32];
    ushort* ldsW1 = &Ws[(64 + wave * 16) * 32];

    for (int bk = 0; bk < K; bk += 32) {
        glds16(AgA + bk, ldsA0);
        glds16(AgB + bk, ldsA1);
        glds16(WgA + bk, ldsW0);
        glds16(WgB + bk, ldsW1);
        __syncthreads();
        short8v a[4], w[4];
#pragma unroll
        for (int m = 0; m < 4; m++) a[m] = *(const short8v*)&As[(wr * 64 + m * 16 + lr) * 32 + kg * 8];
#pragma unroll
        for (int n = 0; n < 4; n++) w[n] = *(const short8v*)&Ws[(wc * 64 + n * 16 + lr) * 32 + kg * 8];
#pragma unroll
        for (int m = 0; m < 4; m++)
#pragma unroll
            for (int n = 0; n < 4; n++)
                acc[m][n] = __builtin_amdgcn_mfma_f32_16x16x32_bf16(a[m], w[n], acc[m][n], 0, 0, 0);
        __syncthreads();
    }

#pragma unroll
    for (int n = 0; n < 4; n++) {
        int col = bcol + wc * 64 + n * 16 + lr;
        float bv = bias[col];
#pragma unroll
        for (int m = 0; m < 4; m++) {
            int row = brow + wr * 64 + m * 16 + kg * 4;
            float4v v = acc[m][n];
#pragma unroll
            for (int j = 0; j < 4; j++)
                C[(size_t)(row + j) * N + col] = v[j] + bv;
        }
    }
}

// Persistent MFMA LSTM: 64 blocks x 128 threads (2 waves), cooperative.
// Block p owns hidden cols [8p, 8p+8). w_hh B-frags pinned in registers.
// pre gate values prefetched one full step ahead (issued before grid.sync).
__global__ __launch_bounds__(128) void k_lstm(
    const float* __restrict__ pre, const float* __restrict__ w_hh,
    const float* __restrict__ c0,
    ushort* __restrict__ hbufA, ushort* __restrict__ hbufB,
    ushort* __restrict__ out_in) {
    __shared__ float G2[64 * 36];   // [b][jj*4+q], row stride 36 floats
    cg::grid_group grid = cg::this_grid();
    int p = blockIdx.x;
    int t = threadIdx.x;
    int wv = t >> 6, lane = t & 63;
    int lr = lane & 15, kg = lane >> 4;
    int q = lr >> 2, u = lr & 3;
    int jj_w = wv * 4 + u;
    int jg_w = p * LJ + jj_w;
    int wrow = q * HIDDEN + jg_w;

    // one-time: load this lane's w_hh B-fragments (fp32 -> bf16)
    short8v wfrag[16];
#pragma unroll
    for (int ks = 0; ks < 16; ks++) {
        const float* src = w_hh + (size_t)wrow * HIDDEN + ks * 32 + kg * 8;
        float4 v0 = *(const float4*)(src);
        float4 v1 = *(const float4*)(src + 4);
        short8v w8;
        w8[0] = (short)f2bf(v0.x); w8[1] = (short)f2bf(v0.y);
        w8[2] = (short)f2bf(v0.z); w8[3] = (short)f2bf(v0.w);
        w8[4] = (short)f2bf(v1.x); w8[5] = (short)f2bf(v1.y);
        w8[6] = (short)f2bf(v1.z); w8[7] = (short)f2bf(v1.w);
        wfrag[ks] = w8;
    }

    // pointwise state: thread t handles (b = i*16 + (t>>3), jj = t&7), i=0..3
    int jj = t & 7;
    int jg = p * LJ + jj;
    int b0 = t >> 3;
    float c_reg[4];
#pragma unroll
    for (int i = 0; i < 4; i++)
        c_reg[i] = c0[(i * 16 + b0) * HIDDEN + jg];

    const float* preb = pre + jg;
    float pv[4][4];   // [i][gate] prefetched for the step about to run
#pragma unroll
    for (int i = 0; i < 4; i++) {
        size_t pb = ((size_t)((i * 16 + b0) * SS + 0)) * G4;
#pragma unroll
        for (int g = 0; g < 4; g++) pv[i][g] = preb[pb + g * HIDDEN];
    }

    for (int s = 0; s < SS; s++) {
        const ushort* hb = (s & 1) ? hbufB : hbufA;
        ushort* hn = (s & 1) ? hbufA : hbufB;

        float4v acc[4];
#pragma unroll
        for (int m = 0; m < 4; m++) acc[m] = (float4v){0.f, 0.f, 0.f, 0.f};
#pragma unroll
        for (int ks = 0; ks < 16; ks++) {
#pragma unroll
            for (int m = 0; m < 4; m++) {
                short8v a = *(const short8v*)(hb + (size_t)(m * 16 + lr) * HIDDEN + ks * 32 + kg * 8);
                acc[m] = __builtin_amdgcn_mfma_f32_16x16x32_bf16(a, wfrag[ks], acc[m], 0, 0, 0);
            }
        }
#pragma unroll
        for (int m = 0; m < 4; m++)
#pragma unroll
            for (int r = 0; r < 4; r++)
                G2[(m * 16 + kg * 4 + r) * 36 + jj_w * 4 + q] = acc[m][r];
        __syncthreads();

#pragma unroll
        for (int i = 0; i < 4; i++) {
            int b = i * 16 + b0;
            float4 gv = *(const float4*)&G2[b * 36 + jj * 4];
            float xi = gv.x + pv[i][0];
            float xf = gv.y + pv[i][1];
            float xg = gv.z + pv[i][2];
            float xo = gv.w + pv[i][3];
            float ig = 1.f / (1.f + __expf(-xi));
            float fg = 1.f / (1.f + __expf(-xf));
            float gg = fast_tanh(xg);
            float og = 1.f / (1.f + __expf(-xo));
            float cn = fg * c_reg[i] + ig * gg;
            float hv = og * fast_tanh(cn);
            c_reg[i] = cn;
            ushort h16 = f2bf(hv);
            out_in[((size_t)(b * SS + s)) * KOUT + jg] = h16;
            if (s + 1 < SS) hn[b * HIDDEN + jg] = h16;
        }

        if (s + 1 < SS) {
            // prefetch next step's pre (a full step + grid.sync of latency hiding)
#pragma unroll
            for (int i = 0; i < 4; i++) {
                size_t pb = ((size_t)((i * 16 + b0) * SS + (s + 1))) * G4;
#pragma unroll
                for (int g = 0; g < 4; g++) pv[i][g] = preb[pb + g * HIDDEN];
            }
            grid.sync();
        }
    }
}

extern "C" void kernel_launch(void* const* d_in, const int* in_sizes, int n_in,
                              void* d_out, int out_size, void* d_ws, size_t ws_size,
                              hipStream_t stream) {
    const int*   tseq = (const int*)d_in[0];
    const float* ctx  = (const float*)d_in[1];
    const float* h0   = (const float*)d_in[2];
    const float* c0   = (const float*)d_in[3];
    const float* emb  = (const float*)d_in[4];
    const float* w_ih = (const float*)d_in[5];
    const float* w_hh = (const float*)d_in[6];
    const float* b_ih = (const float*)d_in[7];
    const float* b_hh = (const float*)d_in[8];
    const float* w_fc = (const float*)d_in[9];
    const float* b_fc = (const float*)d_in[10];
    float* out = (float*)d_out;

    char* wsb = (char*)d_ws;
    size_t off = 0;
    auto alloc = [&](size_t bytes) -> void* {
        void* ptr = wsb + off;
        off = (off + bytes + 255) & ~(size_t)255;
        return ptr;
    };
    ushort* lstm_in  = (ushort*)alloc((size_t)M_ROWS * KIN * 2);
    ushort* w_ih_bf  = (ushort*)alloc((size_t)G4 * KIN * 2);
    ushort* w_fc_bf  = (ushort*)alloc((size_t)VOCAB * KOUT * 2);
    ushort* out_in   = (ushort*)alloc((size_t)M_ROWS * KOUT * 2);
    float*  pre      = (float*)alloc((size_t)M_ROWS * G4 * 4);
    ushort* hbufA    = (ushort*)alloc((size_t)BB * HIDDEN * 2);
    ushort* hbufB    = (ushort*)alloc((size_t)BB * HIDDEN * 2);
    float*  bias_pre = (float*)alloc((size_t)G4 * 4);

    k_f32_to_bf16<<<1024, 256, 0, stream>>>(w_ih, w_ih_bf, G4 * KIN);
    k_f32_to_bf16<<<2048, 256, 0, stream>>>(w_fc, w_fc_bf, VOCAB * KOUT);
    k_build_lstm_in<<<M_ROWS, 256, 0, stream>>>(tseq, emb, ctx, lstm_in);
    k_fill_outin_ctx<<<M_ROWS, 256, 0, stream>>>(ctx, out_in);
    k_prep_small<<<128, 256, 0, stream>>>(b_ih, b_hh, bias_pre, h0, hbufA);

    dim3 g1(G4 / 128, M_ROWS / 128);
    k_gemm_bf16<<<g1, 256, 0, stream>>>(lstm_in, w_ih_bf, bias_pre, pre, M_ROWS, G4, KIN);

    void* args[] = {(void*)&pre, (void*)&w_hh, (void*)&c0,
                    (void*)&hbufA, (void*)&hbufB, (void*)&out_in};
    hipLaunchCooperativeKernel((void*)k_lstm, dim3(64), dim3(128), args, 0, stream);

    dim3 g2(VOCAB / 128, M_ROWS / 128);
    k_gemm_bf16<<<g2, 256, 0, stream>>>(out_in, w_fc_bf, b_fc, out, M_ROWS, VOCAB, KOUT);
}

// Round 4
// 1152.906 us; speedup vs baseline: 2.9361x; 1.2551x over previous
//
#include <hip/hip_runtime.h>
#include <hip/hip_bf16.h>

#define VOCAB 32000
#define EMBED 256
#define HIDDEN 512
#define BB 64
#define SS 64
#define M_ROWS (BB * SS)       /* 4096 */
#define KIN (EMBED + HIDDEN)   /* 768  */
#define G4 (4 * HIDDEN)        /* 2048 */
#define KOUT (2 * HIDDEN)      /* 1024 */
#define NBLK 16                /* LSTM blocks */

typedef __attribute__((ext_vector_type(8))) short short8v;
typedef __attribute__((ext_vector_type(4))) float float4v;
typedef __attribute__((ext_vector_type(2))) unsigned long long ull2;

__device__ __forceinline__ ushort f2bf(float f) {
    union { float f; unsigned u; } v; v.f = f;
    unsigned r = (v.u + 0x7FFFu + ((v.u >> 16) & 1u)) >> 16;
    return (ushort)r;
}

__device__ __forceinline__ float fast_tanh(float x) {
    float xc = fminf(fmaxf(x, -15.f), 15.f);
    float e = __expf(2.f * xc);
    return (e - 1.f) / (e + 1.f);
}

__device__ __forceinline__ void glds16(const ushort* g, ushort* l) {
    __builtin_amdgcn_global_load_lds(
        (const __attribute__((address_space(1))) unsigned int*)(const void*)g,
        (__attribute__((address_space(3))) unsigned int*)(void*)l, 16, 0, 0);
}

__global__ void k_f32_to_bf16(const float* __restrict__ in, ushort* __restrict__ out, int n) {
    int i = blockIdx.x * blockDim.x + threadIdx.x;
    int stride = gridDim.x * blockDim.x;
    for (; i < n; i += stride) out[i] = f2bf(in[i]);
}

__global__ void k_build_lstm_in(const int* __restrict__ tseq, const float* __restrict__ emb,
                                const float* __restrict__ ctx, ushort* __restrict__ lstm_in) {
    int rid = blockIdx.x;             // 0..4095  (= b*64 + s)
    int tok = tseq[rid];
    int b = rid >> 6;
    for (int f = threadIdx.x; f < KIN; f += blockDim.x) {
        float v = (f < EMBED) ? emb[tok * EMBED + f] : ctx[b * HIDDEN + (f - EMBED)];
        lstm_in[(size_t)rid * KIN + f] = f2bf(v);
    }
}

__global__ void k_fill_outin_ctx(const float* __restrict__ ctx, ushort* __restrict__ out_in) {
    int rid = blockIdx.x;
    int b = rid >> 6;
    for (int j = threadIdx.x; j < HIDDEN; j += blockDim.x)
        out_in[(size_t)rid * KOUT + HIDDEN + j] = f2bf(ctx[b * HIDDEN + j]);
}

__global__ void k_prep_small(const float* __restrict__ b_ih, const float* __restrict__ b_hh,
                             float* __restrict__ bias_pre,
                             const float* __restrict__ h0, ushort* __restrict__ hbufA,
                             unsigned* __restrict__ cnt) {
    int i = blockIdx.x * blockDim.x + threadIdx.x;
    if (i == 0) *cnt = 0;   // reset LSTM barrier counter every launch (graph-replay safe)
    if (i < G4) bias_pre[i] = b_ih[i] + b_hh[i];
    if (i < BB * HIDDEN) hbufA[i] = f2bf(h0[i]);
}

// C[M][N] = A[M][K](bf16) @ W[N][K]^T(bf16) + bias[N], fp32 out.
// 128x128 tile, 4 waves (2x2), 4x4 16x16x32 MFMA frags/wave.
// m97 recipe: linear LDS + global_load_lds width-16 staging.
__global__ __launch_bounds__(256) void k_gemm_bf16(
    const ushort* __restrict__ A, const ushort* __restrict__ W,
    const float* __restrict__ bias, float* __restrict__ C,
    int M, int N, int K) {
    __shared__ ushort As[128 * 32];
    __shared__ ushort Ws[128 * 32];
    int t = threadIdx.x;
    int brow = blockIdx.y * 128, bcol = blockIdx.x * 128;
    int wave = t >> 6, lane = t & 63;
    int wr = wave >> 1, wc = wave & 1;
    int lr = lane & 15, kg = lane >> 4;

    float4v acc[4][4];
#pragma unroll
    for (int m = 0; m < 4; m++)
#pragma unroll
        for (int n = 0; n < 4; n++) acc[m][n] = (float4v){0.f, 0.f, 0.f, 0.f};

    int srow = wave * 16 + (lane >> 2);
    int scol = (lane & 3) * 8;
    const ushort* AgA = A + (size_t)(brow + srow) * K + scol;
    const ushort* AgB = A + (size_t)(brow + 64 + srow) * K + scol;
    const ushort* WgA = W + (size_t)(bcol + srow) * K + scol;
    const ushort* WgB = W + (size_t)(bcol + 64 + srow) * K + scol;
    ushort* ldsA0 = &As[(wave * 16) * 32];
    ushort* ldsA1 = &As[(64 + wave * 16) * 32];
    ushort* ldsW0 = &Ws[(wave * 16) * 32];
    ushort* ldsW1 = &Ws[(64 + wave * 16) * 32];

    for (int bk = 0; bk < K; bk += 32) {
        glds16(AgA + bk, ldsA0);
        glds16(AgB + bk, ldsA1);
        glds16(WgA + bk, ldsW0);
        glds16(WgB + bk, ldsW1);
        __syncthreads();
        short8v a[4], w[4];
#pragma unroll
        for (int m = 0; m < 4; m++) a[m] = *(const short8v*)&As[(wr * 64 + m * 16 + lr) * 32 + kg * 8];
#pragma unroll
        for (int n = 0; n < 4; n++) w[n] = *(const short8v*)&Ws[(wc * 64 + n * 16 + lr) * 32 + kg * 8];
#pragma unroll
        for (int m = 0; m < 4; m++)
#pragma unroll
            for (int n = 0; n < 4; n++)
                acc[m][n] = __builtin_amdgcn_mfma_f32_16x16x32_bf16(a[m], w[n], acc[m][n], 0, 0, 0);
        __syncthreads();
    }

#pragma unroll
    for (int n = 0; n < 4; n++) {
        int col = bcol + wc * 64 + n * 16 + lr;
        float bv = bias[col];
#pragma unroll
        for (int m = 0; m < 4; m++) {
            int row = brow + wr * 64 + m * 16 + kg * 4;
            float4v v = acc[m][n];
#pragma unroll
            for (int j = 0; j < 4; j++)
                C[(size_t)(row + j) * N + col] = v[j] + bv;
        }
    }
}

// Persistent MFMA LSTM, custom flush-free barrier.
// 16 blocks x 512 threads (8 waves). Block p owns hidden cols [32p, 32p+32)
// => 128 gate-cols (4 gates x 32 j). Wave w: mh=w>>2 (rows 32), cw2=w&3 (gate).
// w_hh B-frags pinned in VGPRs. h exchanged via agent-scope 8B atomics (bypass
// stale L2, no cache flush). Barrier = monotonic agent atomic counter.
// pre stays L2-cached (read-only, never invalidated).
__global__ __launch_bounds__(512) void k_lstm(
    const float* __restrict__ pre, const float* __restrict__ w_hh,
    const float* __restrict__ c0,
    ushort* __restrict__ hbufA, ushort* __restrict__ hbufB,
    ushort* __restrict__ out_in, unsigned* __restrict__ cnt) {
    __shared__ ushort h_lds[64 * HIDDEN];      // 64KB, XOR-swizzled rows
    __shared__ float G2[64 * 132];             // gates transpose, 33.8KB
    int p = blockIdx.x;
    int t = threadIdx.x;
    int w = t >> 6, lane = t & 63, lr = lane & 15, kg = lane >> 4;
    int mh = w >> 2, cw2 = w & 3;

    // one-time: B-fragments for 2 col-tiles (gate cw2, jj = ci*16+lr)
    short8v wfrag[2][16];
#pragma unroll
    for (int ci = 0; ci < 2; ci++) {
        const float* wrow = w_hh + (size_t)(cw2 * HIDDEN + p * 32 + ci * 16 + lr) * HIDDEN;
#pragma unroll
        for (int ks = 0; ks < 16; ks++) {
            const float* src = wrow + ks * 32 + kg * 8;
            short8v w8;
#pragma unroll
            for (int e = 0; e < 8; e++) w8[e] = (short)f2bf(src[e]);
            wfrag[ci][ks] = w8;
        }
    }

    // pointwise state: thread t -> (b = t>>3, j = 32p + (t&7)*4 .. +4)
    int b = t >> 3, jj0 = (t & 7) * 4, jg0 = p * 32 + jj0;
    float4v c_reg = *(const float4v*)(c0 + (size_t)b * HIDDEN + jg0);
    float4v pv[4];
#pragma unroll
    for (int q = 0; q < 4; q++)
        pv[q] = *(const float4v*)(pre + (size_t)(b * SS) * G4 + q * HIDDEN + jg0);

    char* hl = (char*)h_lds;
    int r_st = t & 63, u0 = t >> 6;   // staging: row, 16B-unit base

    for (int s = 0; s < SS; s++) {
        const ushort* hb = (s & 1) ? hbufB : hbufA;
        ushort* hn = (s & 1) ? hbufA : hbufB;

        // stage h (agent loads -> swizzled LDS)
        {
            const unsigned long long* src = (const unsigned long long*)(hb + (size_t)r_st * HIDDEN);
#pragma unroll
            for (int i = 0; i < 8; i++) {
                int u = u0 + i * 8;
                unsigned long long lo = __hip_atomic_load(src + u * 2,     __ATOMIC_RELAXED, __HIP_MEMORY_SCOPE_AGENT);
                unsigned long long hi = __hip_atomic_load(src + u * 2 + 1, __ATOMIC_RELAXED, __HIP_MEMORY_SCOPE_AGENT);
                int off = (r_st * 1024 + u * 16) ^ ((r_st & 7) << 4);
                ull2 v; v[0] = lo; v[1] = hi;
                *(ull2*)(hl + off) = v;
            }
        }
        __syncthreads();

        float4v acc[2][2];
#pragma unroll
        for (int mi = 0; mi < 2; mi++)
#pragma unroll
            for (int ci = 0; ci < 2; ci++) acc[mi][ci] = (float4v){0.f, 0.f, 0.f, 0.f};
#pragma unroll
        for (int ks = 0; ks < 16; ks++) {
            short8v a[2];
#pragma unroll
            for (int mi = 0; mi < 2; mi++) {
                int row = mh * 32 + mi * 16 + lr;
                int off = (row * 1024 + ks * 64 + kg * 16) ^ ((row & 7) << 4);
                a[mi] = *(const short8v*)(hl + off);
            }
#pragma unroll
            for (int mi = 0; mi < 2; mi++)
#pragma unroll
                for (int ci = 0; ci < 2; ci++)
                    acc[mi][ci] = __builtin_amdgcn_mfma_f32_16x16x32_bf16(a[mi], wfrag[ci][ks], acc[mi][ci], 0, 0, 0);
        }
#pragma unroll
        for (int mi = 0; mi < 2; mi++)
#pragma unroll
            for (int ci = 0; ci < 2; ci++)
#pragma unroll
                for (int r = 0; r < 4; r++)
                    G2[(mh * 32 + mi * 16 + kg * 4 + r) * 132 + cw2 * 32 + ci * 16 + lr] = acc[mi][ci][r];
        __syncthreads();

        // pointwise: 4 cells (same b, j = jg0..jg0+4)
        {
            float4v gq[4];
#pragma unroll
            for (int q = 0; q < 4; q++) gq[q] = *(const float4v*)&G2[b * 132 + q * 32 + jj0];
            unsigned long long hv8 = 0;
#pragma unroll
            for (int e = 0; e < 4; e++) {
                float xi = gq[0][e] + pv[0][e];
                float xf = gq[1][e] + pv[1][e];
                float xg = gq[2][e] + pv[2][e];
                float xo = gq[3][e] + pv[3][e];
                float ig = 1.f / (1.f + __expf(-xi));
                float fg = 1.f / (1.f + __expf(-xf));
                float gg = fast_tanh(xg);
                float og = 1.f / (1.f + __expf(-xo));
                float cn = fg * c_reg[e] + ig * gg;
                float hv = og * fast_tanh(cn);
                c_reg[e] = cn;
                hv8 |= (unsigned long long)f2bf(hv) << (16 * e);
            }
            *(unsigned long long*)(out_in + (size_t)(b * SS + s) * KOUT + jg0) = hv8;
            if (s + 1 < SS) {
                __hip_atomic_store((unsigned long long*)(hn + (size_t)b * HIDDEN + jg0), hv8,
                                   __ATOMIC_RELAXED, __HIP_MEMORY_SCOPE_AGENT);
                // prefetch next step's pre while others finish / barrier spins
#pragma unroll
                for (int q = 0; q < 4; q++)
                    pv[q] = *(const float4v*)(pre + (size_t)(b * SS + s + 1) * G4 + q * HIDDEN + jg0);
            }
        }
        __syncthreads();   // drains all global stores (vmcnt) + G2 reads

        if (s + 1 < SS) {
            if (t == 0) {
                __hip_atomic_fetch_add(cnt, 1u, __ATOMIC_RELEASE, __HIP_MEMORY_SCOPE_AGENT);
                unsigned target = (unsigned)(NBLK * (s + 1));
                while (__hip_atomic_load(cnt, __ATOMIC_ACQUIRE, __HIP_MEMORY_SCOPE_AGENT) < target) {}
            }
            __syncthreads();
        }
    }
}

extern "C" void kernel_launch(void* const* d_in, const int* in_sizes, int n_in,
                              void* d_out, int out_size, void* d_ws, size_t ws_size,
                              hipStream_t stream) {
    const int*   tseq = (const int*)d_in[0];
    const float* ctx  = (const float*)d_in[1];
    const float* h0   = (const float*)d_in[2];
    const float* c0   = (const float*)d_in[3];
    const float* emb  = (const float*)d_in[4];
    const float* w_ih = (const float*)d_in[5];
    const float* w_hh = (const float*)d_in[6];
    const float* b_ih = (const float*)d_in[7];
    const float* b_hh = (const float*)d_in[8];
    const float* w_fc = (const float*)d_in[9];
    const float* b_fc = (const float*)d_in[10];
    float* out = (float*)d_out;

    char* wsb = (char*)d_ws;
    size_t off = 0;
    auto alloc = [&](size_t bytes) -> void* {
        void* ptr = wsb + off;
        off = (off + bytes + 255) & ~(size_t)255;
        return ptr;
    };
    ushort* lstm_in  = (ushort*)alloc((size_t)M_ROWS * KIN * 2);
    ushort* w_ih_bf  = (ushort*)alloc((size_t)G4 * KIN * 2);
    ushort* w_fc_bf  = (ushort*)alloc((size_t)VOCAB * KOUT * 2);
    ushort* out_in   = (ushort*)alloc((size_t)M_ROWS * KOUT * 2);
    float*  pre      = (float*)alloc((size_t)M_ROWS * G4 * 4);
    ushort* hbufA    = (ushort*)alloc((size_t)BB * HIDDEN * 2);
    ushort* hbufB    = (ushort*)alloc((size_t)BB * HIDDEN * 2);
    float*  bias_pre = (float*)alloc((size_t)G4 * 4);
    unsigned* cnt    = (unsigned*)alloc(256);

    k_f32_to_bf16<<<1024, 256, 0, stream>>>(w_ih, w_ih_bf, G4 * KIN);
    k_f32_to_bf16<<<2048, 256, 0, stream>>>(w_fc, w_fc_bf, VOCAB * KOUT);
    k_build_lstm_in<<<M_ROWS, 256, 0, stream>>>(tseq, emb, ctx, lstm_in);
    k_fill_outin_ctx<<<M_ROWS, 256, 0, stream>>>(ctx, out_in);
    k_prep_small<<<128, 256, 0, stream>>>(b_ih, b_hh, bias_pre, h0, hbufA, cnt);

    dim3 g1(G4 / 128, M_ROWS / 128);
    k_gemm_bf16<<<g1, 256, 0, stream>>>(lstm_in, w_ih_bf, bias_pre, pre, M_ROWS, G4, KIN);

    void* args[] = {(void*)&pre, (void*)&w_hh, (void*)&c0,
                    (void*)&hbufA, (void*)&hbufB, (void*)&out_in, (void*)&cnt};
    hipLaunchCooperativeKernel((void*)k_lstm, dim3(NBLK), dim3(512), args, 0, stream);

    dim3 g2(VOCAB / 128, M_ROWS / 128);
    k_gemm_bf16<<<g2, 256, 0, stream>>>(out_in, w_fc_bf, b_fc, out, M_ROWS, VOCAB, KOUT);
}

// Round 6
// 1034.863 us; speedup vs baseline: 3.2710x; 1.1141x over previous
//
#include <hip/hip_runtime.h>
#include <hip/hip_bf16.h>

#define VOCAB 32000
#define EMBED 256
#define HIDDEN 512
#define BB 64
#define SS 64
#define M_ROWS (BB * SS)       /* 4096 */
#define KIN (EMBED + HIDDEN)   /* 768  */
#define G4 (4 * HIDDEN)        /* 2048 */
#define KOUT (2 * HIDDEN)      /* 1024 */
#define NBLK 16                /* LSTM blocks */

typedef __attribute__((ext_vector_type(8))) short short8v;
typedef __attribute__((ext_vector_type(4))) float float4v;
typedef __attribute__((ext_vector_type(2))) unsigned long long ull2;

__device__ __forceinline__ ushort f2bf(float f) {
    union { float f; unsigned u; } v; v.f = f;
    unsigned r = (v.u + 0x7FFFu + ((v.u >> 16) & 1u)) >> 16;
    return (ushort)r;
}

__device__ __forceinline__ float fast_tanh(float x) {
    float xc = fminf(fmaxf(x, -15.f), 15.f);
    float e = __expf(2.f * xc);
    return (e - 1.f) / (e + 1.f);
}

__device__ __forceinline__ void glds16(const ushort* g, ushort* l) {
    __builtin_amdgcn_global_load_lds(
        (const __attribute__((address_space(1))) unsigned int*)(const void*)g,
        (__attribute__((address_space(3))) unsigned int*)(void*)l, 16, 0, 0);
}

__global__ void k_f32_to_bf16(const float* __restrict__ in, ushort* __restrict__ out, int n) {
    int i = blockIdx.x * blockDim.x + threadIdx.x;
    int stride = gridDim.x * blockDim.x;
    for (; i < n; i += stride) out[i] = f2bf(in[i]);
}

__global__ void k_build_lstm_in(const int* __restrict__ tseq, const float* __restrict__ emb,
                                const float* __restrict__ ctx, ushort* __restrict__ lstm_in) {
    int rid = blockIdx.x;             // 0..4095  (= b*64 + s)
    int tok = tseq[rid];
    int b = rid >> 6;
    for (int f = threadIdx.x; f < KIN; f += blockDim.x) {
        float v = (f < EMBED) ? emb[tok * EMBED + f] : ctx[b * HIDDEN + (f - EMBED)];
        lstm_in[(size_t)rid * KIN + f] = f2bf(v);
    }
}

__global__ void k_fill_outin_ctx(const float* __restrict__ ctx, ushort* __restrict__ out_in) {
    int rid = blockIdx.x;
    int b = rid >> 6;
    for (int j = threadIdx.x; j < HIDDEN; j += blockDim.x)
        out_in[(size_t)rid * KOUT + HIDDEN + j] = f2bf(ctx[b * HIDDEN + j]);
}

__global__ void k_prep_small(const float* __restrict__ b_ih, const float* __restrict__ b_hh,
                             float* __restrict__ bias_pre,
                             const float* __restrict__ h0, ushort* __restrict__ hbufA,
                             unsigned* __restrict__ ctrl) {
    int i = blockIdx.x * blockDim.x + threadIdx.x;
    if (i < 256) ctrl[i] = 0;   // reset step flags every launch (graph-replay safe)
    if (i < G4) bias_pre[i] = b_ih[i] + b_hh[i];
    if (i < BB * HIDDEN) hbufA[i] = f2bf(h0[i]);
}

// C[M][N] = A[M][K](bf16) @ W[N][K]^T(bf16) + bias[N], fp32 out.
// 128x128 tile, 4 waves (2x2), 4x4 16x16x32 MFMA frags/wave.
// m97 recipe: linear LDS + global_load_lds width-16 staging.
// 1D grid + bijective XCD swizzle (T1, m204), by-fast linearization so
// consecutive in-chunk blocks share the same W tile (L2 reuse).
__global__ __launch_bounds__(256) void k_gemm_bf16(
    const ushort* __restrict__ A, const ushort* __restrict__ W,
    const float* __restrict__ bias, float* __restrict__ C,
    int M, int N, int K) {
    __shared__ ushort As[128 * 32];
    __shared__ ushort Ws[128 * 32];
    int t = threadIdx.x;

    int nwg = gridDim.x;
    int gy = M >> 7;
    int q = nwg >> 3, r = nwg & 7;
    int xcd = blockIdx.x & 7, idx = blockIdx.x >> 3;
    int wg = (xcd < r) ? xcd * (q + 1) + idx : r * (q + 1) + (xcd - r) * q + idx;
    int by = wg % gy, bx = wg / gy;
    int brow = by * 128, bcol = bx * 128;

    int wave = t >> 6, lane = t & 63;
    int wr = wave >> 1, wc = wave & 1;
    int lr = lane & 15, kg = lane >> 4;

    float4v acc[4][4];
#pragma unroll
    for (int m = 0; m < 4; m++)
#pragma unroll
        for (int n = 0; n < 4; n++) acc[m][n] = (float4v){0.f, 0.f, 0.f, 0.f};

    int srow = wave * 16 + (lane >> 2);
    int scol = (lane & 3) * 8;
    const ushort* AgA = A + (size_t)(brow + srow) * K + scol;
    const ushort* AgB = A + (size_t)(brow + 64 + srow) * K + scol;
    const ushort* WgA = W + (size_t)(bcol + srow) * K + scol;
    const ushort* WgB = W + (size_t)(bcol + 64 + srow) * K + scol;
    ushort* ldsA0 = &As[(wave * 16) * 32];
    ushort* ldsA1 = &As[(64 + wave * 16) * 32];
    ushort* ldsW0 = &Ws[(wave * 16) * 32];
    ushort* ldsW1 = &Ws[(64 + wave * 16) * 32];

    for (int bk = 0; bk < K; bk += 32) {
        glds16(AgA + bk, ldsA0);
        glds16(AgB + bk, ldsA1);
        glds16(WgA + bk, ldsW0);
        glds16(WgB + bk, ldsW1);
        __syncthreads();
        short8v a[4], w[4];
#pragma unroll
        for (int m = 0; m < 4; m++) a[m] = *(const short8v*)&As[(wr * 64 + m * 16 + lr) * 32 + kg * 8];
#pragma unroll
        for (int n = 0; n < 4; n++) w[n] = *(const short8v*)&Ws[(wc * 64 + n * 16 + lr) * 32 + kg * 8];
#pragma unroll
        for (int m = 0; m < 4; m++)
#pragma unroll
            for (int n = 0; n < 4; n++)
                acc[m][n] = __builtin_amdgcn_mfma_f32_16x16x32_bf16(a[m], w[n], acc[m][n], 0, 0, 0);
        __syncthreads();
    }

#pragma unroll
    for (int n = 0; n < 4; n++) {
        int col = bcol + wc * 64 + n * 16 + lr;
        float bv = bias[col];
#pragma unroll
        for (int m = 0; m < 4; m++) {
            int row = brow + wr * 64 + m * 16 + kg * 4;
            float4v v = acc[m][n];
#pragma unroll
            for (int j = 0; j < 4; j++)
                C[(size_t)(row + j) * N + col] = v[j] + bv;
        }
    }
}

// Persistent MFMA LSTM: 16 blocks x 512 threads, cooperative (co-residency).
// Block p owns hidden cols [32p, 32p+32) = 128 gate-cols. w_hh B-frags in VGPRs.
// h exchanged via agent-scope 8B atomics (IF$-coherent, round-4-proven).
// Barrier: DISTRIBUTED per-block flags (64B-padded), published once per step,
// polled in parallel by 16 lanes -- no serialized central RMW chain.
// flags[p*16] = number of steps block p has completed (monotonic, prep-zeroed).
__global__ __launch_bounds__(512) void k_lstm(
    const float* __restrict__ pre, const float* __restrict__ w_hh,
    const float* __restrict__ c0,
    ushort* __restrict__ hbufA, ushort* __restrict__ hbufB,
    ushort* __restrict__ out_in, unsigned* __restrict__ flags) {
    __shared__ ushort h_lds[64 * HIDDEN];      // 64KB, XOR-swizzled rows
    __shared__ float G2[64 * 132];             // gates transpose, 33.8KB
    int p = blockIdx.x;
    int t = threadIdx.x;
    int w = t >> 6, lane = t & 63, lr = lane & 15, kg = lane >> 4;
    int mh = w >> 2, cw2 = w & 3;

    // one-time: B-fragments for 2 col-tiles (gate cw2, jj = ci*16+lr)
    short8v wfrag[2][16];
#pragma unroll
    for (int ci = 0; ci < 2; ci++) {
        const float* wrow = w_hh + (size_t)(cw2 * HIDDEN + p * 32 + ci * 16 + lr) * HIDDEN;
#pragma unroll
        for (int ks = 0; ks < 16; ks++) {
            const float* src = wrow + ks * 32 + kg * 8;
            short8v w8;
#pragma unroll
            for (int e = 0; e < 8; e++) w8[e] = (short)f2bf(src[e]);
            wfrag[ci][ks] = w8;
        }
    }

    // pointwise state: thread t -> (b = t>>3, j = 32p + (t&7)*4 .. +4)
    int b = t >> 3, jj0 = (t & 7) * 4, jg0 = p * 32 + jj0;
    float4v c_reg = *(const float4v*)(c0 + (size_t)b * HIDDEN + jg0);
    float4v pv[4];
#pragma unroll
    for (int qg = 0; qg < 4; qg++)
        pv[qg] = *(const float4v*)(pre + (size_t)(b * SS) * G4 + qg * HIDDEN + jg0);

    char* hl = (char*)h_lds;

    for (int s = 0; s < SS; s++) {
        const ushort* hb = (s & 1) ? hbufB : hbufA;
        ushort* hn = (s & 1) ? hbufA : hbufB;

        // wait: all 16 producers completed step s-1 (parallel flag poll)
        if (s > 0) {
            const unsigned* fp = flags + (lane & 15) * 16;
            unsigned fv;
            do {
                fv = __hip_atomic_load(fp, __ATOMIC_RELAXED, __HIP_MEMORY_SCOPE_AGENT);
            } while (__all((int)(fv >= (unsigned)s)) == 0);
        }

        // stage full h -> swizzled LDS (coalesced: wave w, iter i -> row w*8+i,
        // lane covers bytes [lane*16, +16) as two agent 8B loads)
#pragma unroll
        for (int i = 0; i < 8; i++) {
            int rr = w * 8 + i;
            const unsigned long long* src =
                (const unsigned long long*)(hb + (size_t)rr * HIDDEN + lane * 8);
            unsigned long long lo = __hip_atomic_load(src,     __ATOMIC_RELAXED, __HIP_MEMORY_SCOPE_AGENT);
            unsigned long long hi = __hip_atomic_load(src + 1, __ATOMIC_RELAXED, __HIP_MEMORY_SCOPE_AGENT);
            int off = (rr * 1024 + lane * 16) ^ ((rr & 7) << 4);
            ull2 v; v[0] = lo; v[1] = hi;
            *(ull2*)(hl + off) = v;
        }
        __syncthreads();

        float4v acc[2][2];
#pragma unroll
        for (int mi = 0; mi < 2; mi++)
#pragma unroll
            for (int ci = 0; ci < 2; ci++) acc[mi][ci] = (float4v){0.f, 0.f, 0.f, 0.f};
#pragma unroll
        for (int ks = 0; ks < 16; ks++) {
            short8v a[2];
#pragma unroll
            for (int mi = 0; mi < 2; mi++) {
                int row = mh * 32 + mi * 16 + lr;
                int off = (row * 1024 + ks * 64 + kg * 16) ^ ((row & 7) << 4);
                a[mi] = *(const short8v*)(hl + off);
            }
#pragma unroll
            for (int mi = 0; mi < 2; mi++)
#pragma unroll
                for (int ci = 0; ci < 2; ci++)
                    acc[mi][ci] = __builtin_amdgcn_mfma_f32_16x16x32_bf16(a[mi], wfrag[ci][ks], acc[mi][ci], 0, 0, 0);
        }
#pragma unroll
        for (int mi = 0; mi < 2; mi++)
#pragma unroll
            for (int ci = 0; ci < 2; ci++)
#pragma unroll
                for (int rr = 0; rr < 4; rr++)
                    G2[(mh * 32 + mi * 16 + kg * 4 + rr) * 132 + cw2 * 32 + ci * 16 + lr] = acc[mi][ci][rr];
        __syncthreads();

        // pointwise: 4 cells (same b, j = jg0..jg0+4)
        {
            float4v gq[4];
#pragma unroll
            for (int qg = 0; qg < 4; qg++) gq[qg] = *(const float4v*)&G2[b * 132 + qg * 32 + jj0];
            unsigned long long hv8 = 0;
#pragma unroll
            for (int e = 0; e < 4; e++) {
                float xi = gq[0][e] + pv[0][e];
                float xf = gq[1][e] + pv[1][e];
                float xg = gq[2][e] + pv[2][e];
                float xo = gq[3][e] + pv[3][e];
                float ig = 1.f / (1.f + __expf(-xi));
                float fg = 1.f / (1.f + __expf(-xf));
                float gg = fast_tanh(xg);
                float og = 1.f / (1.f + __expf(-xo));
                float cn = fg * c_reg[e] + ig * gg;
                float hv = og * fast_tanh(cn);
                c_reg[e] = cn;
                hv8 |= (unsigned long long)f2bf(hv) << (16 * e);
            }
            if (s + 1 < SS) {
                __hip_atomic_store((unsigned long long*)(hn + (size_t)b * HIDDEN + jg0), hv8,
                                   __ATOMIC_RELAXED, __HIP_MEMORY_SCOPE_AGENT);
            }
            *(unsigned long long*)(out_in + (size_t)(b * SS + s) * KOUT + jg0) = hv8;
            if (s + 1 < SS) {
                // prefetch next step's pre while others finish
#pragma unroll
                for (int qg = 0; qg < 4; qg++)
                    pv[qg] = *(const float4v*)(pre + (size_t)(b * SS + s + 1) * G4 + qg * HIDDEN + jg0);
            }
        }

        // __syncthreads drains every thread's stores (vmcnt) before publish
        __syncthreads();
        if (t == 0 && s + 1 < SS)
            __hip_atomic_store(flags + p * 16, (unsigned)(s + 1),
                               __ATOMIC_RELEASE, __HIP_MEMORY_SCOPE_AGENT);
    }
}

extern "C" void kernel_launch(void* const* d_in, const int* in_sizes, int n_in,
                              void* d_out, int out_size, void* d_ws, size_t ws_size,
                              hipStream_t stream) {
    const int*   tseq = (const int*)d_in[0];
    const float* ctx  = (const float*)d_in[1];
    const float* h0   = (const float*)d_in[2];
    const float* c0   = (const float*)d_in[3];
    const float* emb  = (const float*)d_in[4];
    const float* w_ih = (const float*)d_in[5];
    const float* w_hh = (const float*)d_in[6];
    const float* b_ih = (const float*)d_in[7];
    const float* b_hh = (const float*)d_in[8];
    const float* w_fc = (const float*)d_in[9];
    const float* b_fc = (const float*)d_in[10];
    float* out = (float*)d_out;

    char* wsb = (char*)d_ws;
    size_t off = 0;
    auto alloc = [&](size_t bytes) -> void* {
        void* ptr = wsb + off;
        off = (off + bytes + 255) & ~(size_t)255;
        return ptr;
    };
    ushort* lstm_in  = (ushort*)alloc((size_t)M_ROWS * KIN * 2);
    ushort* w_ih_bf  = (ushort*)alloc((size_t)G4 * KIN * 2);
    ushort* w_fc_bf  = (ushort*)alloc((size_t)VOCAB * KOUT * 2);
    ushort* out_in   = (ushort*)alloc((size_t)M_ROWS * KOUT * 2);
    float*  pre      = (float*)alloc((size_t)M_ROWS * G4 * 4);
    ushort* hbufA    = (ushort*)alloc((size_t)BB * HIDDEN * 2);
    ushort* hbufB    = (ushort*)alloc((size_t)BB * HIDDEN * 2);
    float*  bias_pre = (float*)alloc((size_t)G4 * 4);
    unsigned* ctrl   = (unsigned*)alloc(1024);

    k_f32_to_bf16<<<1024, 256, 0, stream>>>(w_ih, w_ih_bf, G4 * KIN);
    k_f32_to_bf16<<<2048, 256, 0, stream>>>(w_fc, w_fc_bf, VOCAB * KOUT);
    k_build_lstm_in<<<M_ROWS, 256, 0, stream>>>(tseq, emb, ctx, lstm_in);
    k_fill_outin_ctx<<<M_ROWS, 256, 0, stream>>>(ctx, out_in);
    k_prep_small<<<128, 256, 0, stream>>>(b_ih, b_hh, bias_pre, h0, hbufA, ctrl);

    k_gemm_bf16<<<dim3((G4 / 128) * (M_ROWS / 128)), 256, 0, stream>>>(
        lstm_in, w_ih_bf, bias_pre, pre, M_ROWS, G4, KIN);

    void* args[] = {(void*)&pre, (void*)&w_hh, (void*)&c0,
                    (void*)&hbufA, (void*)&hbufB, (void*)&out_in, (void*)&ctrl};
    hipLaunchCooperativeKernel((void*)k_lstm, dim3(NBLK), dim3(512), args, 0, stream);

    k_gemm_bf16<<<dim3((VOCAB / 128) * (M_ROWS / 128)), 256, 0, stream>>>(
        out_in, w_fc_bf, b_fc, out, M_ROWS, VOCAB, KOUT);
}

// Round 7
// 984.014 us; speedup vs baseline: 3.4400x; 1.0517x over previous
//
#include <hip/hip_runtime.h>
#include <hip/hip_bf16.h>

#define VOCAB 32000
#define EMBED 256
#define HIDDEN 512
#define BB 64
#define SS 64
#define M_ROWS (BB * SS)       /* 4096 */
#define KIN (EMBED + HIDDEN)   /* 768  */
#define G4 (4 * HIDDEN)        /* 2048 */
#define KOUT (2 * HIDDEN)      /* 1024 */
#define NBLK 16                /* LSTM blocks */

typedef __attribute__((ext_vector_type(8))) short short8v;
typedef __attribute__((ext_vector_type(4))) float float4v;
typedef __attribute__((ext_vector_type(4))) unsigned int uint4v;
typedef __attribute__((ext_vector_type(2))) unsigned long long ull2;

__device__ __forceinline__ ushort f2bf(float f) {
    union { float f; unsigned u; } v; v.f = f;
    unsigned r = (v.u + 0x7FFFu + ((v.u >> 16) & 1u)) >> 16;
    return (ushort)r;
}

__device__ __forceinline__ float fast_tanh(float x) {
    float xc = fminf(fmaxf(x, -15.f), 15.f);
    float e = __expf(2.f * xc);
    return (e - 1.f) / (e + 1.f);
}

__device__ __forceinline__ void glds16(const ushort* g, ushort* l) {
    __builtin_amdgcn_global_load_lds(
        (const __attribute__((address_space(1))) unsigned int*)(const void*)g,
        (__attribute__((address_space(3))) unsigned int*)(void*)l, 16, 0, 0);
}

__global__ void k_f32_to_bf16(const float* __restrict__ in, ushort* __restrict__ out, int n) {
    int i = blockIdx.x * blockDim.x + threadIdx.x;
    int stride = gridDim.x * blockDim.x;
    for (; i < n; i += stride) out[i] = f2bf(in[i]);
}

__global__ void k_build_lstm_in(const int* __restrict__ tseq, const float* __restrict__ emb,
                                const float* __restrict__ ctx, ushort* __restrict__ lstm_in) {
    int rid = blockIdx.x;             // 0..4095  (= b*64 + s)
    int tok = tseq[rid];
    int b = rid >> 6;
    for (int f = threadIdx.x; f < KIN; f += blockDim.x) {
        float v = (f < EMBED) ? emb[tok * EMBED + f] : ctx[b * HIDDEN + (f - EMBED)];
        lstm_in[(size_t)rid * KIN + f] = f2bf(v);
    }
}

__global__ void k_fill_outin_ctx(const float* __restrict__ ctx, ushort* __restrict__ out_in) {
    int rid = blockIdx.x;
    int b = rid >> 6;
    for (int j = threadIdx.x; j < HIDDEN; j += blockDim.x)
        out_in[(size_t)rid * KOUT + HIDDEN + j] = f2bf(ctx[b * HIDDEN + j]);
}

__global__ void k_prep_small(const float* __restrict__ b_ih, const float* __restrict__ b_hh,
                             float* __restrict__ bias_pre,
                             const float* __restrict__ h0, ushort* __restrict__ hbufA,
                             unsigned* __restrict__ ctrl) {
    int i = blockIdx.x * blockDim.x + threadIdx.x;
    if (i < 256) ctrl[i] = 0;   // reset step flags every launch (graph-replay safe)
    if (i < G4) bias_pre[i] = b_ih[i] + b_hh[i];
    if (i < BB * HIDDEN) hbufA[i] = f2bf(h0[i]);
}

// C[M][N] = A[M][K](bf16) @ W[N][K]^T(bf16) + bias[N], fp32 out.
// 128x128 tile, 4 waves (2x2), 4x4 16x16x32 MFMA frags/wave.
// m97 recipe: linear LDS + global_load_lds width-16 staging.
// Epilogue: LDS-transposed, 16B/lane full-line C stores (no L2 RFO).
__global__ __launch_bounds__(256) void k_gemm_bf16(
    const ushort* __restrict__ A, const ushort* __restrict__ W,
    const float* __restrict__ bias, float* __restrict__ C,
    int M, int N, int K) {
    __shared__ __align__(16) char smem[17408];   // As(8K)+Ws(8K) / epi(17K) aliased
    ushort* As = (ushort*)smem;
    ushort* Ws = As + 4096;
    float* epi = (float*)smem;                   // [wave][16][68]
    int t = threadIdx.x;

    int nwg = gridDim.x;
    int gy = M >> 7;
    int q = nwg >> 3, r = nwg & 7;
    int xcd = blockIdx.x & 7, idx = blockIdx.x >> 3;
    int wg = (xcd < r) ? xcd * (q + 1) + idx : r * (q + 1) + (xcd - r) * q + idx;
    int by = wg % gy, bx = wg / gy;
    int brow = by * 128, bcol = bx * 128;

    int wave = t >> 6, lane = t & 63;
    int wr = wave >> 1, wc = wave & 1;
    int lr = lane & 15, kg = lane >> 4;

    float4v acc[4][4];
#pragma unroll
    for (int m = 0; m < 4; m++)
#pragma unroll
        for (int n = 0; n < 4; n++) acc[m][n] = (float4v){0.f, 0.f, 0.f, 0.f};

    int srow = wave * 16 + (lane >> 2);
    int scol = (lane & 3) * 8;
    const ushort* AgA = A + (size_t)(brow + srow) * K + scol;
    const ushort* AgB = A + (size_t)(brow + 64 + srow) * K + scol;
    const ushort* WgA = W + (size_t)(bcol + srow) * K + scol;
    const ushort* WgB = W + (size_t)(bcol + 64 + srow) * K + scol;
    ushort* ldsA0 = &As[(wave * 16) * 32];
    ushort* ldsA1 = &As[(64 + wave * 16) * 32];
    ushort* ldsW0 = &Ws[(wave * 16) * 32];
    ushort* ldsW1 = &Ws[(64 + wave * 16) * 32];

    for (int bk = 0; bk < K; bk += 32) {
        glds16(AgA + bk, ldsA0);
        glds16(AgB + bk, ldsA1);
        glds16(WgA + bk, ldsW0);
        glds16(WgB + bk, ldsW1);
        __syncthreads();
        short8v a[4], w[4];
#pragma unroll
        for (int m = 0; m < 4; m++) a[m] = *(const short8v*)&As[(wr * 64 + m * 16 + lr) * 32 + kg * 8];
#pragma unroll
        for (int n = 0; n < 4; n++) w[n] = *(const short8v*)&Ws[(wc * 64 + n * 16 + lr) * 32 + kg * 8];
#pragma unroll
        for (int m = 0; m < 4; m++)
#pragma unroll
            for (int n = 0; n < 4; n++)
                acc[m][n] = __builtin_amdgcn_mfma_f32_16x16x32_bf16(a[m], w[n], acc[m][n], 0, 0, 0);
        __syncthreads();
    }

    // ---- epilogue: LDS transpose -> coalesced full-line stores ----
    float bv[4];
#pragma unroll
    for (int n = 0; n < 4; n++) bv[n] = bias[bcol + wc * 64 + n * 16 + lr];

    int er = t >> 3;          // 0..31
    int cu = t & 7;           // 0..7
    int wrg = er >> 4;        // 0..1
    int rloc = er & 15;
    int c16 = cu * 16;
    int wcg = c16 >> 6;
    int cloc = c16 & 63;
    const float* esrc = &epi[((wrg * 2 + wcg) * 16 + rloc) * 68 + cloc];

#pragma unroll
    for (int m = 0; m < 4; m++) {
        if (m > 0) __syncthreads();
#pragma unroll
        for (int n = 0; n < 4; n++)
#pragma unroll
            for (int j = 0; j < 4; j++)
                epi[(wave * 16 + kg * 4 + j) * 68 + n * 16 + lr] = acc[m][n][j] + bv[n];
        __syncthreads();
        float* dst = C + (size_t)(brow + wrg * 64 + m * 16 + rloc) * N + bcol + c16;
#pragma unroll
        for (int e = 0; e < 4; e++)
            ((float4*)dst)[e] = ((const float4*)esrc)[e];
    }
}

// Persistent MFMA LSTM: 16 blocks x 512 threads, cooperative (co-residency).
// Block p owns hidden cols [32p, 32p+32) = 128 gate-cols. w_hh B-frags in VGPRs.
// h published via agent-scope 8B atomic stores; consumed via WIDE sc0+sc1
// global_load_dwordx4 (L1+L2 bypass, IF$-coherent, wave-coalesced).
// Barrier: distributed per-block flags (64B-padded), parallel lane poll.
__global__ __launch_bounds__(512) void k_lstm(
    const float* __restrict__ pre, const float* __restrict__ w_hh,
    const float* __restrict__ c0,
    ushort* __restrict__ hbufA, ushort* __restrict__ hbufB,
    ushort* __restrict__ out_in, unsigned* __restrict__ flags) {
    __shared__ ushort h_lds[64 * HIDDEN];      // 64KB, XOR-swizzled rows
    __shared__ float G2[64 * 132];             // gates transpose, 33.8KB
    int p = blockIdx.x;
    int t = threadIdx.x;
    int w = t >> 6, lane = t & 63, lr = lane & 15, kg = lane >> 4;
    int mh = w >> 2, cw2 = w & 3;

    // one-time: B-fragments for 2 col-tiles (gate cw2, jj = ci*16+lr)
    short8v wfrag[2][16];
#pragma unroll
    for (int ci = 0; ci < 2; ci++) {
        const float* wrow = w_hh + (size_t)(cw2 * HIDDEN + p * 32 + ci * 16 + lr) * HIDDEN;
#pragma unroll
        for (int ks = 0; ks < 16; ks++) {
            const float* src = wrow + ks * 32 + kg * 8;
            short8v w8;
#pragma unroll
            for (int e = 0; e < 8; e++) w8[e] = (short)f2bf(src[e]);
            wfrag[ci][ks] = w8;
        }
    }

    // pointwise state: thread t -> (b = t>>3, j = 32p + (t&7)*4 .. +4)
    int b = t >> 3, jj0 = (t & 7) * 4, jg0 = p * 32 + jj0;
    float4v c_reg = *(const float4v*)(c0 + (size_t)b * HIDDEN + jg0);
    float4v pv[4];
#pragma unroll
    for (int qg = 0; qg < 4; qg++)
        pv[qg] = *(const float4v*)(pre + (size_t)(b * SS) * G4 + qg * HIDDEN + jg0);

    char* hl = (char*)h_lds;

    for (int s = 0; s < SS; s++) {
        const ushort* hb = (s & 1) ? hbufB : hbufA;
        ushort* hn = (s & 1) ? hbufA : hbufB;

        // wait: all 16 producers completed step s-1 (parallel flag poll)
        if (s > 0) {
            const unsigned* fp = flags + (lane & 15) * 16;
            unsigned fv;
            do {
                fv = __hip_atomic_load(fp, __ATOMIC_RELAXED, __HIP_MEMORY_SCOPE_AGENT);
            } while (__all((int)(fv >= (unsigned)s)) == 0);
        }

        // stage full h -> swizzled LDS via wide agent-coherent loads
        {
            uint4v vb[8];
#pragma unroll
            for (int i = 0; i < 8; i++) {
                int rr = w * 8 + i;
                const void* src = hb + (size_t)rr * HIDDEN + lane * 8;
                asm volatile("global_load_dwordx4 %0, %1, off sc0 sc1"
                             : "=&v"(vb[i]) : "v"(src));
            }
            asm volatile("s_waitcnt vmcnt(0)" ::: "memory");
#pragma unroll
            for (int i = 0; i < 8; i++) {
                int rr = w * 8 + i;
                int off = (rr * 1024 + lane * 16) ^ ((rr & 7) << 4);
                *(uint4v*)(hl + off) = vb[i];
            }
        }
        __syncthreads();

        float4v acc[2][2];
#pragma unroll
        for (int mi = 0; mi < 2; mi++)
#pragma unroll
            for (int ci = 0; ci < 2; ci++) acc[mi][ci] = (float4v){0.f, 0.f, 0.f, 0.f};
#pragma unroll
        for (int ks = 0; ks < 16; ks++) {
            short8v a[2];
#pragma unroll
            for (int mi = 0; mi < 2; mi++) {
                int row = mh * 32 + mi * 16 + lr;
                int off = (row * 1024 + ks * 64 + kg * 16) ^ ((row & 7) << 4);
                a[mi] = *(const short8v*)(hl + off);
            }
#pragma unroll
            for (int mi = 0; mi < 2; mi++)
#pragma unroll
                for (int ci = 0; ci < 2; ci++)
                    acc[mi][ci] = __builtin_amdgcn_mfma_f32_16x16x32_bf16(a[mi], wfrag[ci][ks], acc[mi][ci], 0, 0, 0);
        }
#pragma unroll
        for (int mi = 0; mi < 2; mi++)
#pragma unroll
            for (int ci = 0; ci < 2; ci++)
#pragma unroll
                for (int rr = 0; rr < 4; rr++)
                    G2[(mh * 32 + mi * 16 + kg * 4 + rr) * 132 + cw2 * 32 + ci * 16 + lr] = acc[mi][ci][rr];
        __syncthreads();

        // pointwise: 4 cells (same b, j = jg0..jg0+4)
        {
            float4v gq[4];
#pragma unroll
            for (int qg = 0; qg < 4; qg++) gq[qg] = *(const float4v*)&G2[b * 132 + qg * 32 + jj0];
            unsigned long long hv8 = 0;
#pragma unroll
            for (int e = 0; e < 4; e++) {
                float xi = gq[0][e] + pv[0][e];
                float xf = gq[1][e] + pv[1][e];
                float xg = gq[2][e] + pv[2][e];
                float xo = gq[3][e] + pv[3][e];
                float ig = 1.f / (1.f + __expf(-xi));
                float fg = 1.f / (1.f + __expf(-xf));
                float gg = fast_tanh(xg);
                float og = 1.f / (1.f + __expf(-xo));
                float cn = fg * c_reg[e] + ig * gg;
                float hv = og * fast_tanh(cn);
                c_reg[e] = cn;
                hv8 |= (unsigned long long)f2bf(hv) << (16 * e);
            }
            if (s + 1 < SS) {
                __hip_atomic_store((unsigned long long*)(hn + (size_t)b * HIDDEN + jg0), hv8,
                                   __ATOMIC_RELAXED, __HIP_MEMORY_SCOPE_AGENT);
            }
            *(unsigned long long*)(out_in + (size_t)(b * SS + s) * KOUT + jg0) = hv8;
            if (s + 1 < SS) {
                // prefetch next step's pre while others finish
#pragma unroll
                for (int qg = 0; qg < 4; qg++)
                    pv[qg] = *(const float4v*)(pre + (size_t)(b * SS + s + 1) * G4 + qg * HIDDEN + jg0);
            }
        }

        // __syncthreads drains every thread's stores (vmcnt) before publish
        __syncthreads();
        if (t == 0 && s + 1 < SS)
            __hip_atomic_store(flags + p * 16, (unsigned)(s + 1),
                               __ATOMIC_RELEASE, __HIP_MEMORY_SCOPE_AGENT);
    }
}

extern "C" void kernel_launch(void* const* d_in, const int* in_sizes, int n_in,
                              void* d_out, int out_size, void* d_ws, size_t ws_size,
                              hipStream_t stream) {
    const int*   tseq = (const int*)d_in[0];
    const float* ctx  = (const float*)d_in[1];
    const float* h0   = (const float*)d_in[2];
    const float* c0   = (const float*)d_in[3];
    const float* emb  = (const float*)d_in[4];
    const float* w_ih = (const float*)d_in[5];
    const float* w_hh = (const float*)d_in[6];
    const float* b_ih = (const float*)d_in[7];
    const float* b_hh = (const float*)d_in[8];
    const float* w_fc = (const float*)d_in[9];
    const float* b_fc = (const float*)d_in[10];
    float* out = (float*)d_out;

    char* wsb = (char*)d_ws;
    size_t off = 0;
    auto alloc = [&](size_t bytes) -> void* {
        void* ptr = wsb + off;
        off = (off + bytes + 255) & ~(size_t)255;
        return ptr;
    };
    ushort* lstm_in  = (ushort*)alloc((size_t)M_ROWS * KIN * 2);
    ushort* w_ih_bf  = (ushort*)alloc((size_t)G4 * KIN * 2);
    ushort* w_fc_bf  = (ushort*)alloc((size_t)VOCAB * KOUT * 2);
    ushort* out_in   = (ushort*)alloc((size_t)M_ROWS * KOUT * 2);
    float*  pre      = (float*)alloc((size_t)M_ROWS * G4 * 4);
    ushort* hbufA    = (ushort*)alloc((size_t)BB * HIDDEN * 2);
    ushort* hbufB    = (ushort*)alloc((size_t)BB * HIDDEN * 2);
    float*  bias_pre = (float*)alloc((size_t)G4 * 4);
    unsigned* ctrl   = (unsigned*)alloc(1024);

    k_f32_to_bf16<<<1024, 256, 0, stream>>>(w_ih, w_ih_bf, G4 * KIN);
    k_f32_to_bf16<<<2048, 256, 0, stream>>>(w_fc, w_fc_bf, VOCAB * KOUT);
    k_build_lstm_in<<<M_ROWS, 256, 0, stream>>>(tseq, emb, ctx, lstm_in);
    k_fill_outin_ctx<<<M_ROWS, 256, 0, stream>>>(ctx, out_in);
    k_prep_small<<<128, 256, 0, stream>>>(b_ih, b_hh, bias_pre, h0, hbufA, ctrl);

    k_gemm_bf16<<<dim3((G4 / 128) * (M_ROWS / 128)), 256, 0, stream>>>(
        lstm_in, w_ih_bf, bias_pre, pre, M_ROWS, G4, KIN);

    void* args[] = {(void*)&pre, (void*)&w_hh, (void*)&c0,
                    (void*)&hbufA, (void*)&hbufB, (void*)&out_in, (void*)&ctrl};
    hipLaunchCooperativeKernel((void*)k_lstm, dim3(NBLK), dim3(512), args, 0, stream);

    k_gemm_bf16<<<dim3((VOCAB / 128) * (M_ROWS / 128)), 256, 0, stream>>>(
        out_in, w_fc_bf, b_fc, out, M_ROWS, VOCAB, KOUT);
}